// Round 8
// baseline (120.129 us; speedup 1.0000x reference)
//
#include <hip/hip_runtime.h>
#include <math.h>

#define Bn 8
#define Qn 20
#define Pn 12
#define Nn 4096
#define Gn 2048
#define Mn 1280   /* Q*FACTOR */
#define Fn 64
#define KNB 7     /* K_NEIGHBORS - 1 */
#define NCOST 160
#define NCHA 160  /* chamfer A blocks: outer recon chunks of 64 */
#define NCHB 256  /* chamfer B blocks: outer gt chunks of 64 */
#define NREP 20   /* 8 groups per block */
#define NBLK 596  /* 160 + 160 + 256 + 20 */
#define C2_TARGET 425 /* 8 JV + 416 chamfer + 1 rep-last */
#define SCOPE_AGENT __HIP_MEMORY_SCOPE_AGENT

// ---------------- workspace layout (32-bit words) ----------------
// cham  : 0      (1920)   ns: 1920  dd: 3840  cost: 5760  cnt: 7680
// base  : 7783   NEVER WRITTEN -> holds the fill poison pattern
// doneB : 7808+16b (b<8)  per-batch cost counters, EACH ON ITS OWN LINE
// c2    : 7936   completion counter (own line)
// repslt: 7952   rep result slot (own line)
// repc  : 7968   rep sub-counter (own line)
// jvslot: 8000+16b (b<8)  {cls,par,pvd} per batch, own line each
// slotA : 8192+16c  (c<160) {c1,c2} per A chunk, own line each   [ends 10752]
// slotB : 10752+16c (c<256) {c1,c2} per B chunk, own line each   [ends 14848]
// rep   : 14848  (160) per-group repulsion partials
//
// R14: R13 was chamfer-VALU-bound at 40% machine util: 104 chamfer blocks =
// 104 busy CUs; A-block = 8 waves x 1024 pairs x 26cy = 22us @ 2 waves/SIMD,
// CUs with 2 chamfer blocks = 44us == measured 42.5. Total chamfer work is
// only ~17M SIMD-cycles (7us if spread). Fix: outer chunks 256->64, inner
// split 2->8-way (one WAVE per inner eighth: part=tid>>6, outer pt=tid&63;
// LDS reads stay wave-uniform broadcasts). 596 blocks, all co-resident
// (32KB LDS, 4 blocks/CU) -> JV spin safety unchanged. 8-way min combine is
// order-exact; per-chunk sum tree is now 64-wide (reordering empirically
// benign R7-R13). Cost/JV/rep paths byte-identical to R13.

__device__ __forceinline__ void ast(float* p, float v) {
    __hip_atomic_store(p, v, __ATOMIC_RELAXED, SCOPE_AGENT);
}
__device__ __forceinline__ float ald(const float* p) {
    return __hip_atomic_load(p, __ATOMIC_RELAXED, SCOPE_AGENT);
}

__device__ __forceinline__ int rdlane_i(int v, int l) {
    return __builtin_amdgcn_readlane(v, l);
}
__device__ __forceinline__ float rdlane_f(float v, int l) {
    return __int_as_float(__builtin_amdgcn_readlane(__float_as_int(v), l));
}
// full-wave min via DPP (VALU pipe); result valid in lane 63.
__device__ __forceinline__ unsigned wave_min_u32(unsigned x) {
    unsigned t;
    t = (unsigned)__builtin_amdgcn_update_dpp((int)0xFFFFFFFF, (int)x, 0x111, 0xF, 0xF, false);
    x = t < x ? t : x;
    t = (unsigned)__builtin_amdgcn_update_dpp((int)0xFFFFFFFF, (int)x, 0x112, 0xF, 0xF, false);
    x = t < x ? t : x;
    t = (unsigned)__builtin_amdgcn_update_dpp((int)0xFFFFFFFF, (int)x, 0x114, 0xF, 0xF, false);
    x = t < x ? t : x;
    t = (unsigned)__builtin_amdgcn_update_dpp((int)0xFFFFFFFF, (int)x, 0x118, 0xF, 0xF, false);
    x = t < x ? t : x;
    t = (unsigned)__builtin_amdgcn_update_dpp((int)0xFFFFFFFF, (int)x, 0x142, 0xF, 0xF, false);
    x = t < x ? t : x;
    t = (unsigned)__builtin_amdgcn_update_dpp((int)0xFFFFFFFF, (int)x, 0x143, 0xF, 0xF, false);
    x = t < x ? t : x;
    return x;
}

// one release-RMW per contributor; the 425th sums all slots (fixed order).
__device__ __forceinline__ void bump_c2(float* ws, float* out, unsigned init) {
    unsigned* c2P = (unsigned*)(ws + 7936);
    unsigned old = __hip_atomic_fetch_add(c2P, 1u, __ATOMIC_ACQ_REL, SCOPE_AGENT);
    if (old - init == (unsigned)(C2_TARGET - 1)) {
        float a0 = 0.f, a1 = 0.f, a2 = 0.f, a4 = 0.f, a5 = 0.f;
#pragma unroll
        for (int b = 0; b < 8; ++b) {
            a0 += ald(ws + 8000 + 16 * b + 0);
            a1 += ald(ws + 8000 + 16 * b + 1);
            a2 += ald(ws + 8000 + 16 * b + 2);
        }
#pragma unroll 8
        for (int c = 0; c < NCHA; ++c) {
            a4 += ald(ws + 8192 + 16 * c + 0);
            a5 += ald(ws + 8192 + 16 * c + 1);
        }
#pragma unroll 8
        for (int c = 0; c < NCHB; ++c) {
            a4 += ald(ws + 10752 + 16 * c + 0);
            a5 += ald(ws + 10752 + 16 * c + 1);
        }
        float a3 = ald(ws + 7952);
        out[0] = a0 + 0.5f * a1 + 20.f * a2 + a3 + a4 + a5;
        // restore counters to poison baseline (harmless if re-poisoned)
        unsigned* w = (unsigned*)ws;
        __hip_atomic_store(&w[7936], init, __ATOMIC_RELAXED, SCOPE_AGENT);
        __hip_atomic_store(&w[7968], init, __ATOMIC_RELAXED, SCOPE_AGENT);
#pragma unroll
        for (int b = 0; b < 8; ++b)
            __hip_atomic_store(&w[7808 + 16 * b], init, __ATOMIC_RELAXED, SCOPE_AGENT);
    }
}

__global__ __launch_bounds__(512, 2)
void fused_kernel(const float* __restrict__ pred_logits,
                  const float* __restrict__ pred_normals,
                  const float* __restrict__ pred_distances,
                  const float* __restrict__ gt_normals,
                  const float* __restrict__ gt_distances,
                  const float* __restrict__ points,
                  const int*   __restrict__ gt_masks,
                  const float* __restrict__ recon,
                  const float* __restrict__ gt,
                  float* __restrict__ ws,
                  float* __restrict__ out) {
    __shared__ __align__(16) float smem[8192];   // 32 KB
    __shared__ int sflag;
    const int blk = blockIdx.x;
    const int tid = threadIdx.x;

    float* cham = ws;
    float* ns   = ws + 1920;
    float* dd   = ws + 3840;
    float* cost = ws + 5760;
    float* cnt  = ws + 7680;
    unsigned* baseP = (unsigned*)(ws + 7783);
    unsigned* repcP = (unsigned*)(ws + 7968);
    float* rep_part = ws + 14848;

    const unsigned init = __hip_atomic_load(baseP, __ATOMIC_RELAXED, SCOPE_AGENT);

    if (blk < NCOST) {
        // ================= cost path (bitwise == R13; XCD-swizzled mapping) =========
        const int b = blk & 7, q = blk >> 3;   // blk%8 = batch -> one XCD's L2
        const float nx = pred_normals[(b * Qn + q) * 3 + 0];
        const float ny = pred_normals[(b * Qn + q) * 3 + 1];
        const float nz = pred_normals[(b * Qn + q) * 3 + 2];
        const float dq = pred_distances[b * Qn + q];

        if (tid < 256) {
            float accs[Pn], accw[Pn];
#pragma unroll
            for (int p = 0; p < Pn; ++p) { accs[p] = 0.f; accw[p] = 0.f; }
            const float* ptb = points + (size_t)b * Nn * 3;
            const int*   mb  = gt_masks + (size_t)b * Pn * Nn;
            for (int n = tid; n < Nn; n += 256) {
                float px = ptb[n * 3 + 0], py = ptb[n * 3 + 1], pz = ptb[n * 3 + 2];
                float pp = fabsf(px * nx + py * ny + pz * nz - dq);
#pragma unroll
                for (int p = 0; p < Pn; ++p) {
                    float m = (float)mb[(size_t)p * Nn + n];
                    accs[p] += pp * m;
                    accw[p] += m;
                }
            }
#pragma unroll
            for (int p = 0; p < Pn; ++p) {
                smem[p * 256 + tid] = accs[p];
                smem[(p + Pn) * 256 + tid] = accw[p];
            }
        }
        __syncthreads();
        for (int off = 128; off > 0; off >>= 1) {
            if (tid < off) {
#pragma unroll
                for (int r = 0; r < 2 * Pn; ++r) smem[r * 256 + tid] += smem[r * 256 + tid + off];
            }
            __syncthreads();
        }
        if (tid < Pn) {
            const int p = tid;
            float c  = smem[(p + Pn) * 256];
            float cv = smem[p * 256] / fmaxf(c, 1.f);
            float gnx = gt_normals[(b * Pn + p) * 3 + 0];
            float gny = gt_normals[(b * Pn + p) * 3 + 1];
            float gnz = gt_normals[(b * Pn + p) * 3 + 2];
            float nsim = 1.f - fabsf(nx * gnx + ny * gny + nz * gnz);
            float ddv  = fabsf(dq - gt_distances[b * Pn + p]);
            int idx = (b * Qn + q) * Pn + p;
            ast(&cham[idx], cv);
            ast(&ns[idx],   nsim);
            ast(&dd[idx],   ddv);
            ast(&cost[idx], nsim + 0.5f * ddv + 5.f * ((c > 0.f) ? cv : 1.f));
            if (q == 0) ast(&cnt[b * Pn + p], c);
        }
        __syncthreads();   // each wave drains its stores before tid0 publishes
        if (tid == 0)
            __hip_atomic_fetch_add((unsigned*)(ws + 7808 + 16 * b), 1u,
                                   __ATOMIC_RELEASE, SCOPE_AGENT);
        if (blk >= 8) return;

        // ---- JV block: batch b == blk (q==0 swizzled block); spin on its 20 ----
        if (tid == 0) {
            unsigned* dB = (unsigned*)(ws + 7808 + 16 * blk);
            while (__hip_atomic_load(dB, __ATOMIC_RELAXED, SCOPE_AGENT) - init != 20u)
                __builtin_amdgcn_s_sleep(2);
            (void)__hip_atomic_load(dB, __ATOMIC_ACQUIRE, SCOPE_AGENT);
        }
        __syncthreads();

        if (tid < 64) {
            const int b2 = blk;
            const int t = tid;
            const int col = t;
            const bool isCol = (col >= 1 && col <= Qn);

            float cr[Pn];
#pragma unroll
            for (int k = 0; k < Pn; ++k) cr[k] = 0.f;
            if (isCol) {
                const float* cb = cost + ((size_t)b2 * Qn + (col - 1)) * Pn;
#pragma unroll
                for (int k = 0; k < Pn; ++k) cr[k] = ald(&cb[k]);
            }

            float v = 0.f, u = 0.f, minv = 0.f;
            int way = 0, p = 0;

            for (int i = 1; i <= Pn; ++i) {
                minv = 1e30f;
                bool used = false;
                bool rowInPath = false;
                int j0s = 0;
                while (true) {
                    if (col == j0s) used = true;
                    int i0s = (j0s == 0) ? i : rdlane_i(p, j0s);
                    if (t == i0s) rowInPath = true;
                    float u_i0 = rdlane_f(u, i0s);
                    const int bs = i0s - 1;
                    float l10 = (bs & 1) ? cr[1]  : cr[0];
                    float l11 = (bs & 1) ? cr[3]  : cr[2];
                    float l12 = (bs & 1) ? cr[5]  : cr[4];
                    float l13 = (bs & 1) ? cr[7]  : cr[6];
                    float l14 = (bs & 1) ? cr[9]  : cr[8];
                    float l15 = (bs & 1) ? cr[11] : cr[10];
                    float l20 = (bs & 2) ? l11 : l10;
                    float l21 = (bs & 2) ? l13 : l12;
                    float l22 = (bs & 2) ? l15 : l14;
                    float cij = (bs >= 8) ? l22 : ((bs >= 4) ? l21 : l20);
                    if (isCol && !used) {
                        float cur = cij - u_i0 - v;
                        if (cur < minv) { minv = cur; way = j0s; }
                    }
                    float mv = (isCol && !used) ? minv : 1e30f;
                    unsigned kb = __float_as_uint(mv);
                    kb = ((int)kb < 0) ? ~kb : (kb | 0x80000000u);
                    kb = (kb & ~31u) | (unsigned)(col & 31);
                    unsigned kmin = (unsigned)rdlane_i((int)wave_min_u32(kb), 63);
                    int j1 = (int)(kmin & 31u);
                    float delta = rdlane_f(minv, j1);
                    if (used || col == 0) v -= delta;
                    else if (isCol)       minv -= delta;
                    if (rowInPath)        u += delta;
                    j0s = j1;
                    int pj0 = rdlane_i(p, j0s);
                    if (pj0 == 0) break;
                }
                while (j0s != 0) {
                    int wj = rdlane_i(way, j0s);
                    int pw = (wj == 0) ? i : rdlane_i(p, wj);
                    if (col == j0s) p = pw;
                    j0s = wj;
                }
            }

            float cls = 0.f, par = 0.f, pvd = 0.f;
            if (isCol) {
                float x = pred_logits[b2 * Qn + (col - 1)];
                float tgt = (p > 0) ? 1.f : 0.f;
                cls = fmaxf(x, 0.f) - x * tgt + log1pf(expf(-fabsf(x)));
                if (p > 0) {
                    int idx = (b2 * Qn + (col - 1)) * Pn + (p - 1);
                    par = ald(&ns[idx]) + ald(&dd[idx]);
                    pvd = (ald(&cnt[b2 * Pn + (p - 1)]) > 0.f) ? ald(&cham[idx]) : 0.f;
                }
            }
            for (int off = 32; off > 0; off >>= 1) {
                cls += __shfl_down(cls, off);
                par += __shfl_down(par, off);
                pvd += __shfl_down(pvd, off);
            }
            if (t == 0) {
                float* slot = ws + 8000 + 16 * b2;   // private line
                ast(slot + 0, cls / (float)(Bn * Qn));
                ast(slot + 1, par / (float)(Bn * Pn));
                ast(slot + 2, pvd / (float)(Bn * Pn));
                bump_c2(ws, out, init);
            }
        }
        return;
    } else if (blk < NCOST + NCHA + NCHB) {
        // ============ chamfer: inner cloud in LDS, 8-way intra-block split ==========
        // one WAVE per inner-eighth: part = tid>>6 (wave id), outer pt = tid&63.
        const int a0 = blk - NCOST;
        const bool isA = (a0 < NCHA);
        // XCD swizzle: chunk placed so blk%8 == its batch
        int chunk;
        if (isA) { int r = a0;        chunk = (r & 7) * 20 + (r >> 3); }
        else     { int r = a0 - NCHA; chunk = (r & 7) * 32 + (r >> 3); }
        const int lt = tid & 63;
        const int part = tid >> 6;           // 0..7
        const int idx = chunk * 64 + lt;     // outer point index (flat over B*pts)
        const float* inner;
        const float* op;
        int ninner;
        float scale;
        float* slot;
        if (isA) {
            const int b = idx / Mn;          // outer = recon, inner = gt[b] (2048)
            inner = gt + (size_t)b * Gn * 3;
            op = recon + (size_t)idx * 3;
            ninner = Gn;
            scale = 0.5f / (float)(Bn * Mn);
            slot = ws + 8192 + 16 * chunk;
        } else {
            const int b = idx / Gn;          // outer = gt, inner = recon[b] (1280)
            inner = recon + (size_t)b * Mn * 3;
            op = gt + (size_t)idx * 3;
            ninner = Mn;
            scale = 0.5f / (float)(Bn * Gn);
            slot = ws + 10752 + 16 * chunk;
        }
        float4* tile = reinterpret_cast<float4*>(smem);
        for (int j = tid; j < ninner; j += 512) {
            const float* ip = inner + j * 3;
            float4 tv;
            tv.x = ip[0]; tv.y = ip[1]; tv.z = ip[2]; tv.w = 0.f;
            tile[j] = tv;
        }
        __syncthreads();
        const float x = op[0], y = op[1], z = op[2];
        const int span = ninner >> 3;        // 256 (A) or 160 (B)
        const int j0 = part * span, j1 = j0 + span;
        float m1 = 3.4e38f, m2 = 3.4e38f;
#pragma unroll 4
        for (int j = j0; j < j1; ++j) {
            float4 tv = tile[j];
            float dx = x - tv.x, dy = y - tv.y, dz = z - tv.z;
            float d1 = fabsf(dx) + fabsf(dy) + fabsf(dz);
            float d2 = dx * dx + dy * dy + dz * dz;
            m1 = fminf(m1, d1); m2 = fminf(m2, d2);
        }
        __syncthreads();                     // tile dead; reuse smem
        float* s1 = smem;                    // [0,512)
        float* s2 = smem + 512;              // [512,1024)
        s1[tid] = m1;
        s2[tid] = m2;
        __syncthreads();
        float* t1 = smem + 1024;             // [1024,1088)
        float* t2 = smem + 1088;             // [1088,1152)
        if (tid < 64) {
            float M1 = s1[tid], M2 = s2[tid];
#pragma unroll
            for (int pp = 1; pp < 8; ++pp) {     // min: order-exact
                M1 = fminf(M1, s1[pp * 64 + tid]);
                M2 = fminf(M2, s2[pp * 64 + tid]);
            }
            t1[tid] = M1 * scale;
            t2[tid] = M2 * scale;
        }
        __syncthreads();
        for (int off = 32; off > 0; off >>= 1) {
            if (tid < off) { t1[tid] += t1[tid + off]; t2[tid] += t2[tid + off]; }
            __syncthreads();
        }
        if (tid == 0) {
            ast(slot + 0, t1[0]);
            ast(slot + 1, t2[0]);
            bump_c2(ws, out, init);
        }
        return;
    }

    // ================= repulsion: 8 waves/block, 20 blocks =================
    {
        const int wave = tid >> 6, lane = tid & 63;
        const int g = (blk - (NCOST + NCHA + NCHB)) * 8 + wave;
        float* xs = smem + wave * 192;
        float* ys = xs + 64;
        float* zs = xs + 128;
        const float* base = recon + (size_t)g * Fn * 3;
        xs[lane] = base[lane * 3 + 0];
        ys[lane] = base[lane * 3 + 1];
        zs[lane] = base[lane * 3 + 2];
        float best[KNB];
#pragma unroll
        for (int k = 0; k < KNB; ++k) best[k] = 3.4e38f;
        const float xi = xs[lane], yi = ys[lane], zi = zs[lane];
        for (int j = 0; j < Fn; ++j) {
            float dx = xi - xs[j], dy = yi - ys[j], dz = zi - zs[j];
            float d2 = dx * dx + dy * dy + dz * dz;
            d2 = (j == lane) ? 3.4e38f : d2;
#pragma unroll
            for (int k = 0; k < KNB; ++k) {
                float lo = fminf(best[k], d2);
                float hi = fmaxf(best[k], d2);
                best[k] = lo;
                d2 = hi;
            }
        }
        float sum = 0.f;
#pragma unroll
        for (int k = 0; k < KNB; ++k) {
            float dn = fmaxf(best[k], 1e-12f);
            float w  = expf(-dn / (0.03f * 0.03f));
            sum += (0.07f - sqrtf(dn)) * w;
        }
        for (int off = 32; off > 0; off >>= 1) sum += __shfl_down(sum, off);
        if (lane == 0) ast(&rep_part[g], fmaxf(sum / (float)(Fn * KNB), 0.f));
        __syncthreads();   // drain stores
        if (tid == 0) {
            unsigned old = __hip_atomic_fetch_add(repcP, 1u, __ATOMIC_ACQ_REL, SCOPE_AGENT);
            sflag = (old - init == (unsigned)(NREP - 1)) ? 1 : 0;
        }
        __syncthreads();
        if (sflag) {
            // exact rep reduce tree (tid<256 active; all 512 at barriers)
            float* s1 = smem + 2048;
            if (tid < 256)
                s1[tid] = (tid < Bn * Qn) ? ald(&rep_part[tid]) / (float)(Bn * Qn) : 0.f;
            __syncthreads();
            for (int off = 128; off > 0; off >>= 1) {
                if (tid < off) s1[tid] += s1[tid + off];
                __syncthreads();
            }
            if (tid == 0) {
                ast(ws + 7952, s1[0]);
                bump_c2(ws, out, init);
            }
        }
    }
}

extern "C" void kernel_launch(void* const* d_in, const int* in_sizes, int n_in,
                              void* d_out, int out_size, void* d_ws, size_t ws_size,
                              hipStream_t stream) {
    const float* pred_logits    = (const float*)d_in[0];
    const float* pred_normals   = (const float*)d_in[1];
    const float* pred_distances = (const float*)d_in[2];
    const float* gt_normals     = (const float*)d_in[3];
    const float* gt_distances   = (const float*)d_in[4];
    const int*   gt_masks       = (const int*)d_in[5];
    const float* points         = (const float*)d_in[6];
    const float* recon          = (const float*)d_in[7];
    const float* gt             = (const float*)d_in[8];
    // d_in[9] (gt_index) is unused by the reference.

    fused_kernel<<<NBLK, 512, 0, stream>>>(pred_logits, pred_normals, pred_distances,
                                           gt_normals, gt_distances, points, gt_masks,
                                           recon, gt, (float*)d_ws, (float*)d_out);
}

// Round 9
// 110.388 us; speedup vs baseline: 1.0882x; 1.0882x over previous
//
#include <hip/hip_runtime.h>
#include <math.h>

#define Bn 8
#define Qn 20
#define Pn 12
#define Nn 4096
#define Gn 2048
#define Mn 1280   /* Q*FACTOR */
#define Fn 64
#define KNB 7     /* K_NEIGHBORS - 1 */
#define NCOST 160
#define NCHA 160  /* chamfer A blocks: outer recon chunks of 64 */
#define NCHB 256  /* chamfer B blocks: outer gt chunks of 64 */
#define NREP 20   /* 8 groups per block */
#define NBLK 596  /* 160 + 160 + 256 + 20 */
#define C2_TARGET 17  /* 8 JV + 8 cham-level2 + 1 rep-last */
#define SCOPE_AGENT __HIP_MEMORY_SCOPE_AGENT

// ---------------- workspace layout (32-bit words) ----------------
// cham  : 0      (1920)   ns: 1920  dd: 3840  cost: 5760  cnt: 7680
// base  : 7783   NEVER WRITTEN -> holds the fill poison pattern
// doneB : 7808+16b (b<8)  per-batch cost counters, EACH ON ITS OWN LINE
// c2    : 7936   completion counter (own line)
// repslt: 7952   rep result slot (own line)
// repc  : 7968   rep sub-counter (own line)
// jvslot: 8000+16b (b<8)  {cls,par,pvd} per batch, own line each
// slotA : 8192+16c  (c<160) {c1,c2} per A chunk, own line each   [ends 10752]
// slotB : 10752+16c (c<256) {c1,c2} per B chunk, own line each   [ends 14848]
// rep   : 14848  (160) per-group repulsion partials
// chamc : 15360+16i (i<8) level-1 chamfer counters (52 each), own line each
//
// R15: R13->R14 delta isolated the tail: the SINGLE-THREADED assembler reads
// all slot lines uncached (~900cy each): R13 233 loads ~7.5us, R14 857 loads
// ~27us -> kernel 42.5/55 both = work + assembler. Fix: (1) last contributor's
// whole 512-thread block parallel-loads the 425 slot lines into LDS (~1us),
// tid0 then sums IN THE EXACT R14 ORDER from LDS (bitwise-identical result);
// (2) two-level cham counters: 416 blocks bump chamc[blk&7] (52 each, spread
// 8 lines); the 8 level-1 finishers bump c2 -> C2_TARGET 425->17. Release
// chain: slot stores -> chamc ACQ_REL -> c2 ACQ_REL -> assembler acquire.
// Work paths (cost/JV/rep/chamfer) byte-identical to R14.

__device__ __forceinline__ void ast(float* p, float v) {
    __hip_atomic_store(p, v, __ATOMIC_RELAXED, SCOPE_AGENT);
}
__device__ __forceinline__ float ald(const float* p) {
    return __hip_atomic_load(p, __ATOMIC_RELAXED, SCOPE_AGENT);
}

__device__ __forceinline__ int rdlane_i(int v, int l) {
    return __builtin_amdgcn_readlane(v, l);
}
__device__ __forceinline__ float rdlane_f(float v, int l) {
    return __int_as_float(__builtin_amdgcn_readlane(__float_as_int(v), l));
}
// full-wave min via DPP (VALU pipe); result valid in lane 63.
__device__ __forceinline__ unsigned wave_min_u32(unsigned x) {
    unsigned t;
    t = (unsigned)__builtin_amdgcn_update_dpp((int)0xFFFFFFFF, (int)x, 0x111, 0xF, 0xF, false);
    x = t < x ? t : x;
    t = (unsigned)__builtin_amdgcn_update_dpp((int)0xFFFFFFFF, (int)x, 0x112, 0xF, 0xF, false);
    x = t < x ? t : x;
    t = (unsigned)__builtin_amdgcn_update_dpp((int)0xFFFFFFFF, (int)x, 0x114, 0xF, 0xF, false);
    x = t < x ? t : x;
    t = (unsigned)__builtin_amdgcn_update_dpp((int)0xFFFFFFFF, (int)x, 0x118, 0xF, 0xF, false);
    x = t < x ? t : x;
    t = (unsigned)__builtin_amdgcn_update_dpp((int)0xFFFFFFFF, (int)x, 0x142, 0xF, 0xF, false);
    x = t < x ? t : x;
    t = (unsigned)__builtin_amdgcn_update_dpp((int)0xFFFFFFFF, (int)x, 0x143, 0xF, 0xF, false);
    x = t < x ? t : x;
    return x;
}

// returns true iff caller is the LAST of the 17 level-2 contributors.
__device__ __forceinline__ bool bump_c2(float* ws, unsigned init) {
    unsigned* c2P = (unsigned*)(ws + 7936);
    unsigned old = __hip_atomic_fetch_add(c2P, 1u, __ATOMIC_ACQ_REL, SCOPE_AGENT);
    return (old - init == (unsigned)(C2_TARGET - 1));
}

// whole-block parallel slot gather + tid0 canonical-order sum (bitwise == R14).
__device__ __forceinline__ void assemble(float* ws, float* out, unsigned init,
                                         float* ld, int tid) {
    if (tid < 8) {
        ld[3 * tid + 0] = ald(ws + 8000 + 16 * tid + 0);
        ld[3 * tid + 1] = ald(ws + 8000 + 16 * tid + 1);
        ld[3 * tid + 2] = ald(ws + 8000 + 16 * tid + 2);
    } else if (tid < 168) {
        int c = tid - 8;
        ld[24 + 2 * c + 0] = ald(ws + 8192 + 16 * c + 0);
        ld[24 + 2 * c + 1] = ald(ws + 8192 + 16 * c + 1);
    } else if (tid < 424) {
        int c = tid - 168;
        ld[344 + 2 * c + 0] = ald(ws + 10752 + 16 * c + 0);
        ld[344 + 2 * c + 1] = ald(ws + 10752 + 16 * c + 1);
    } else if (tid == 424) {
        ld[856] = ald(ws + 7952);
    }
    __syncthreads();
    if (tid == 0) {
        float a0 = 0.f, a1 = 0.f, a2 = 0.f, a4 = 0.f, a5 = 0.f;
#pragma unroll
        for (int b = 0; b < 8; ++b) {
            a0 += ld[3 * b + 0];
            a1 += ld[3 * b + 1];
            a2 += ld[3 * b + 2];
        }
#pragma unroll 8
        for (int c = 0; c < NCHA; ++c) {
            a4 += ld[24 + 2 * c + 0];
            a5 += ld[24 + 2 * c + 1];
        }
#pragma unroll 8
        for (int c = 0; c < NCHB; ++c) {
            a4 += ld[344 + 2 * c + 0];
            a5 += ld[344 + 2 * c + 1];
        }
        float a3 = ld[856];
        out[0] = a0 + 0.5f * a1 + 20.f * a2 + a3 + a4 + a5;
        // restore counters to poison baseline (harmless if re-poisoned)
        unsigned* w = (unsigned*)ws;
        __hip_atomic_store(&w[7936], init, __ATOMIC_RELAXED, SCOPE_AGENT);
        __hip_atomic_store(&w[7968], init, __ATOMIC_RELAXED, SCOPE_AGENT);
#pragma unroll
        for (int b = 0; b < 8; ++b) {
            __hip_atomic_store(&w[7808 + 16 * b], init, __ATOMIC_RELAXED, SCOPE_AGENT);
            __hip_atomic_store(&w[15360 + 16 * b], init, __ATOMIC_RELAXED, SCOPE_AGENT);
        }
    }
}

__global__ __launch_bounds__(512, 2)
void fused_kernel(const float* __restrict__ pred_logits,
                  const float* __restrict__ pred_normals,
                  const float* __restrict__ pred_distances,
                  const float* __restrict__ gt_normals,
                  const float* __restrict__ gt_distances,
                  const float* __restrict__ points,
                  const int*   __restrict__ gt_masks,
                  const float* __restrict__ recon,
                  const float* __restrict__ gt,
                  float* __restrict__ ws,
                  float* __restrict__ out) {
    __shared__ __align__(16) float smem[8192];   // 32 KB
    __shared__ int sflag;
    __shared__ int fflag;
    const int blk = blockIdx.x;
    const int tid = threadIdx.x;
    float* const ld = smem + 4096;               // 857 floats, barrier-separated reuse

    float* cham = ws;
    float* ns   = ws + 1920;
    float* dd   = ws + 3840;
    float* cost = ws + 5760;
    float* cnt  = ws + 7680;
    unsigned* baseP = (unsigned*)(ws + 7783);
    unsigned* repcP = (unsigned*)(ws + 7968);
    float* rep_part = ws + 14848;

    const unsigned init = __hip_atomic_load(baseP, __ATOMIC_RELAXED, SCOPE_AGENT);

    if (blk < NCOST) {
        // ================= cost path (bitwise == R14; XCD-swizzled mapping) =========
        const int b = blk & 7, q = blk >> 3;   // blk%8 = batch -> one XCD's L2
        const float nx = pred_normals[(b * Qn + q) * 3 + 0];
        const float ny = pred_normals[(b * Qn + q) * 3 + 1];
        const float nz = pred_normals[(b * Qn + q) * 3 + 2];
        const float dq = pred_distances[b * Qn + q];

        if (tid < 256) {
            float accs[Pn], accw[Pn];
#pragma unroll
            for (int p = 0; p < Pn; ++p) { accs[p] = 0.f; accw[p] = 0.f; }
            const float* ptb = points + (size_t)b * Nn * 3;
            const int*   mb  = gt_masks + (size_t)b * Pn * Nn;
            for (int n = tid; n < Nn; n += 256) {
                float px = ptb[n * 3 + 0], py = ptb[n * 3 + 1], pz = ptb[n * 3 + 2];
                float pp = fabsf(px * nx + py * ny + pz * nz - dq);
#pragma unroll
                for (int p = 0; p < Pn; ++p) {
                    float m = (float)mb[(size_t)p * Nn + n];
                    accs[p] += pp * m;
                    accw[p] += m;
                }
            }
#pragma unroll
            for (int p = 0; p < Pn; ++p) {
                smem[p * 256 + tid] = accs[p];
                smem[(p + Pn) * 256 + tid] = accw[p];
            }
        }
        __syncthreads();
        for (int off = 128; off > 0; off >>= 1) {
            if (tid < off) {
#pragma unroll
                for (int r = 0; r < 2 * Pn; ++r) smem[r * 256 + tid] += smem[r * 256 + tid + off];
            }
            __syncthreads();
        }
        if (tid < Pn) {
            const int p = tid;
            float c  = smem[(p + Pn) * 256];
            float cv = smem[p * 256] / fmaxf(c, 1.f);
            float gnx = gt_normals[(b * Pn + p) * 3 + 0];
            float gny = gt_normals[(b * Pn + p) * 3 + 1];
            float gnz = gt_normals[(b * Pn + p) * 3 + 2];
            float nsim = 1.f - fabsf(nx * gnx + ny * gny + nz * gnz);
            float ddv  = fabsf(dq - gt_distances[b * Pn + p]);
            int idx = (b * Qn + q) * Pn + p;
            ast(&cham[idx], cv);
            ast(&ns[idx],   nsim);
            ast(&dd[idx],   ddv);
            ast(&cost[idx], nsim + 0.5f * ddv + 5.f * ((c > 0.f) ? cv : 1.f));
            if (q == 0) ast(&cnt[b * Pn + p], c);
        }
        __syncthreads();   // each wave drains its stores before tid0 publishes
        if (tid == 0)
            __hip_atomic_fetch_add((unsigned*)(ws + 7808 + 16 * b), 1u,
                                   __ATOMIC_RELEASE, SCOPE_AGENT);
        if (blk >= 8) return;

        // ---- JV block: batch b == blk (q==0 swizzled block); spin on its 20 ----
        if (tid == 0) {
            unsigned* dB = (unsigned*)(ws + 7808 + 16 * blk);
            while (__hip_atomic_load(dB, __ATOMIC_RELAXED, SCOPE_AGENT) - init != 20u)
                __builtin_amdgcn_s_sleep(2);
            (void)__hip_atomic_load(dB, __ATOMIC_ACQUIRE, SCOPE_AGENT);
        }
        __syncthreads();

        if (tid < 64) {
            const int b2 = blk;
            const int t = tid;
            const int col = t;
            const bool isCol = (col >= 1 && col <= Qn);

            float cr[Pn];
#pragma unroll
            for (int k = 0; k < Pn; ++k) cr[k] = 0.f;
            if (isCol) {
                const float* cb = cost + ((size_t)b2 * Qn + (col - 1)) * Pn;
#pragma unroll
                for (int k = 0; k < Pn; ++k) cr[k] = ald(&cb[k]);
            }

            float v = 0.f, u = 0.f, minv = 0.f;
            int way = 0, p = 0;

            for (int i = 1; i <= Pn; ++i) {
                minv = 1e30f;
                bool used = false;
                bool rowInPath = false;
                int j0s = 0;
                while (true) {
                    if (col == j0s) used = true;
                    int i0s = (j0s == 0) ? i : rdlane_i(p, j0s);
                    if (t == i0s) rowInPath = true;
                    float u_i0 = rdlane_f(u, i0s);
                    const int bs = i0s - 1;
                    float l10 = (bs & 1) ? cr[1]  : cr[0];
                    float l11 = (bs & 1) ? cr[3]  : cr[2];
                    float l12 = (bs & 1) ? cr[5]  : cr[4];
                    float l13 = (bs & 1) ? cr[7]  : cr[6];
                    float l14 = (bs & 1) ? cr[9]  : cr[8];
                    float l15 = (bs & 1) ? cr[11] : cr[10];
                    float l20 = (bs & 2) ? l11 : l10;
                    float l21 = (bs & 2) ? l13 : l12;
                    float l22 = (bs & 2) ? l15 : l14;
                    float cij = (bs >= 8) ? l22 : ((bs >= 4) ? l21 : l20);
                    if (isCol && !used) {
                        float cur = cij - u_i0 - v;
                        if (cur < minv) { minv = cur; way = j0s; }
                    }
                    float mv = (isCol && !used) ? minv : 1e30f;
                    unsigned kb = __float_as_uint(mv);
                    kb = ((int)kb < 0) ? ~kb : (kb | 0x80000000u);
                    kb = (kb & ~31u) | (unsigned)(col & 31);
                    unsigned kmin = (unsigned)rdlane_i((int)wave_min_u32(kb), 63);
                    int j1 = (int)(kmin & 31u);
                    float delta = rdlane_f(minv, j1);
                    if (used || col == 0) v -= delta;
                    else if (isCol)       minv -= delta;
                    if (rowInPath)        u += delta;
                    j0s = j1;
                    int pj0 = rdlane_i(p, j0s);
                    if (pj0 == 0) break;
                }
                while (j0s != 0) {
                    int wj = rdlane_i(way, j0s);
                    int pw = (wj == 0) ? i : rdlane_i(p, wj);
                    if (col == j0s) p = pw;
                    j0s = wj;
                }
            }

            float cls = 0.f, par = 0.f, pvd = 0.f;
            if (isCol) {
                float x = pred_logits[b2 * Qn + (col - 1)];
                float tgt = (p > 0) ? 1.f : 0.f;
                cls = fmaxf(x, 0.f) - x * tgt + log1pf(expf(-fabsf(x)));
                if (p > 0) {
                    int idx = (b2 * Qn + (col - 1)) * Pn + (p - 1);
                    par = ald(&ns[idx]) + ald(&dd[idx]);
                    pvd = (ald(&cnt[b2 * Pn + (p - 1)]) > 0.f) ? ald(&cham[idx]) : 0.f;
                }
            }
            for (int off = 32; off > 0; off >>= 1) {
                cls += __shfl_down(cls, off);
                par += __shfl_down(par, off);
                pvd += __shfl_down(pvd, off);
            }
            if (t == 0) {
                float* slot = ws + 8000 + 16 * b2;   // private line
                ast(slot + 0, cls / (float)(Bn * Qn));
                ast(slot + 1, par / (float)(Bn * Pn));
                ast(slot + 2, pvd / (float)(Bn * Pn));
                fflag = bump_c2(ws, init) ? 1 : 0;
            }
        }
        __syncthreads();
        if (fflag) assemble(ws, out, init, ld, tid);
        return;
    } else if (blk < NCOST + NCHA + NCHB) {
        // ============ chamfer: inner cloud in LDS, 8-way intra-block split ==========
        // one WAVE per inner-eighth: part = tid>>6 (wave id), outer pt = tid&63.
        const int a0 = blk - NCOST;
        const bool isA = (a0 < NCHA);
        // XCD swizzle: chunk placed so blk%8 == its batch
        int chunk;
        if (isA) { int r = a0;        chunk = (r & 7) * 20 + (r >> 3); }
        else     { int r = a0 - NCHA; chunk = (r & 7) * 32 + (r >> 3); }
        const int lt = tid & 63;
        const int part = tid >> 6;           // 0..7
        const int idx = chunk * 64 + lt;     // outer point index (flat over B*pts)
        const float* inner;
        const float* op;
        int ninner;
        float scale;
        float* slot;
        if (isA) {
            const int b = idx / Mn;          // outer = recon, inner = gt[b] (2048)
            inner = gt + (size_t)b * Gn * 3;
            op = recon + (size_t)idx * 3;
            ninner = Gn;
            scale = 0.5f / (float)(Bn * Mn);
            slot = ws + 8192 + 16 * chunk;
        } else {
            const int b = idx / Gn;          // outer = gt, inner = recon[b] (1280)
            inner = recon + (size_t)b * Mn * 3;
            op = gt + (size_t)idx * 3;
            ninner = Mn;
            scale = 0.5f / (float)(Bn * Gn);
            slot = ws + 10752 + 16 * chunk;
        }
        float4* tile = reinterpret_cast<float4*>(smem);
        for (int j = tid; j < ninner; j += 512) {
            const float* ip = inner + j * 3;
            float4 tv;
            tv.x = ip[0]; tv.y = ip[1]; tv.z = ip[2]; tv.w = 0.f;
            tile[j] = tv;
        }
        __syncthreads();
        const float x = op[0], y = op[1], z = op[2];
        const int span = ninner >> 3;        // 256 (A) or 160 (B)
        const int j0 = part * span, j1 = j0 + span;
        float m1 = 3.4e38f, m2 = 3.4e38f;
#pragma unroll 4
        for (int j = j0; j < j1; ++j) {
            float4 tv = tile[j];
            float dx = x - tv.x, dy = y - tv.y, dz = z - tv.z;
            float d1 = fabsf(dx) + fabsf(dy) + fabsf(dz);
            float d2 = dx * dx + dy * dy + dz * dz;
            m1 = fminf(m1, d1); m2 = fminf(m2, d2);
        }
        __syncthreads();                     // tile dead; reuse smem
        float* s1 = smem;                    // [0,512)
        float* s2 = smem + 512;              // [512,1024)
        s1[tid] = m1;
        s2[tid] = m2;
        __syncthreads();
        float* t1 = smem + 1024;             // [1024,1088)
        float* t2 = smem + 1088;             // [1088,1152)
        if (tid < 64) {
            float M1 = s1[tid], M2 = s2[tid];
#pragma unroll
            for (int pp = 1; pp < 8; ++pp) {     // min: order-exact
                M1 = fminf(M1, s1[pp * 64 + tid]);
                M2 = fminf(M2, s2[pp * 64 + tid]);
            }
            t1[tid] = M1 * scale;
            t2[tid] = M2 * scale;
        }
        __syncthreads();
        for (int off = 32; off > 0; off >>= 1) {
            if (tid < off) { t1[tid] += t1[tid + off]; t2[tid] += t2[tid + off]; }
            __syncthreads();
        }
        if (tid == 0) {
            ast(slot + 0, t1[0]);
            ast(slot + 1, t2[0]);
            // level-1 bump (8 spread lines, 52 each); finisher bumps c2
            unsigned* l1 = (unsigned*)(ws + 15360 + 16 * (blk & 7));
            unsigned old = __hip_atomic_fetch_add(l1, 1u, __ATOMIC_ACQ_REL, SCOPE_AGENT);
            int last = 0;
            if (old - init == 51u) last = bump_c2(ws, init) ? 1 : 0;
            fflag = last;
        }
        __syncthreads();
        if (fflag) assemble(ws, out, init, ld, tid);
        return;
    }

    // ================= repulsion: 8 waves/block, 20 blocks =================
    {
        const int wave = tid >> 6, lane = tid & 63;
        const int g = (blk - (NCOST + NCHA + NCHB)) * 8 + wave;
        float* xs = smem + wave * 192;
        float* ys = xs + 64;
        float* zs = xs + 128;
        const float* base = recon + (size_t)g * Fn * 3;
        xs[lane] = base[lane * 3 + 0];
        ys[lane] = base[lane * 3 + 1];
        zs[lane] = base[lane * 3 + 2];
        float best[KNB];
#pragma unroll
        for (int k = 0; k < KNB; ++k) best[k] = 3.4e38f;
        const float xi = xs[lane], yi = ys[lane], zi = zs[lane];
        for (int j = 0; j < Fn; ++j) {
            float dx = xi - xs[j], dy = yi - ys[j], dz = zi - zs[j];
            float d2 = dx * dx + dy * dy + dz * dz;
            d2 = (j == lane) ? 3.4e38f : d2;
#pragma unroll
            for (int k = 0; k < KNB; ++k) {
                float lo = fminf(best[k], d2);
                float hi = fmaxf(best[k], d2);
                best[k] = lo;
                d2 = hi;
            }
        }
        float sum = 0.f;
#pragma unroll
        for (int k = 0; k < KNB; ++k) {
            float dn = fmaxf(best[k], 1e-12f);
            float w  = expf(-dn / (0.03f * 0.03f));
            sum += (0.07f - sqrtf(dn)) * w;
        }
        for (int off = 32; off > 0; off >>= 1) sum += __shfl_down(sum, off);
        if (lane == 0) ast(&rep_part[g], fmaxf(sum / (float)(Fn * KNB), 0.f));
        __syncthreads();   // drain stores
        if (tid == 0) {
            unsigned old = __hip_atomic_fetch_add(repcP, 1u, __ATOMIC_ACQ_REL, SCOPE_AGENT);
            sflag = (old - init == (unsigned)(NREP - 1)) ? 1 : 0;
            fflag = 0;
        }
        __syncthreads();
        if (sflag) {
            // exact rep reduce tree (tid<256 active; all 512 at barriers)
            float* s1 = smem + 2048;
            if (tid < 256)
                s1[tid] = (tid < Bn * Qn) ? ald(&rep_part[tid]) / (float)(Bn * Qn) : 0.f;
            __syncthreads();
            for (int off = 128; off > 0; off >>= 1) {
                if (tid < off) s1[tid] += s1[tid + off];
                __syncthreads();
            }
            if (tid == 0) {
                ast(ws + 7952, s1[0]);
                fflag = bump_c2(ws, init) ? 1 : 0;
            }
        }
        __syncthreads();
        if (fflag) assemble(ws, out, init, ld, tid);
    }
}

extern "C" void kernel_launch(void* const* d_in, const int* in_sizes, int n_in,
                              void* d_out, int out_size, void* d_ws, size_t ws_size,
                              hipStream_t stream) {
    const float* pred_logits    = (const float*)d_in[0];
    const float* pred_normals   = (const float*)d_in[1];
    const float* pred_distances = (const float*)d_in[2];
    const float* gt_normals     = (const float*)d_in[3];
    const float* gt_distances   = (const float*)d_in[4];
    const int*   gt_masks       = (const int*)d_in[5];
    const float* points         = (const float*)d_in[6];
    const float* recon          = (const float*)d_in[7];
    const float* gt             = (const float*)d_in[8];
    // d_in[9] (gt_index) is unused by the reference.

    fused_kernel<<<NBLK, 512, 0, stream>>>(pred_logits, pred_normals, pred_distances,
                                           gt_normals, gt_distances, points, gt_masks,
                                           recon, gt, (float*)d_ws, (float*)d_out);
}